// Round 7
// baseline (359.889 us; speedup 1.0000x reference)
//
#include <hip/hip_runtime.h>

// MMSE-PIC detector: B=32768, M=16, S=8, QAM16 Gray, 2 iterations.
// Round 13: 2 batches per wave (register-level ILP). R7/R12 falsified
// DS-bandwidth-bound; R6..R12 support latency-serialization: each wave
// issues ~19% of its life, stalled on ~45 dependent LDS round-trips, and
// resident blocks/CU are pinned at ~3-4 regardless of geometry. So hide
// latency INSIDE the wave: every phase is emitted as two independent A/B
// instruction streams (separate LDS slots, duplicated registers) between
// shared fences; the scheduler overlaps A's lgkmcnt stalls with B's VALU.
// No loop back-edge (R10 spill trap), no extra DS ops, R11 shell kept.

#define EPS_F 1e-4f
#define INV_SQRT10 0.31622776601683794f
#define WSYNC() __builtin_amdgcn_wave_barrier()

__device__ __forceinline__ float rcpf(float x) { return __builtin_amdgcn_rcpf(x); }
__device__ __forceinline__ float rsqf(float x) { return __builtin_amdgcn_rsqf(x); }
__device__ __forceinline__ float rdlane(float v, int l) {
    return __uint_as_float(__builtin_amdgcn_readlane(__float_as_uint(v), l));
}
template<int OFF>
__device__ __forceinline__ float swzf(float v) {
    return __uint_as_float(__builtin_amdgcn_ds_swizzle(__float_as_uint(v), OFF));
}
// xor-butterfly swizzle patterns (BitMode: offset = xor<<10 | or<<5 | and)
#define SWX1 0x041F
#define SWX2 0x081F
#define SWX4 0x101F

__device__ __forceinline__ float pt_re(int p) {
    return (1.0f - 2.0f * (float)((p >> 3) & 1)) * (1.0f + 2.0f * (float)((p >> 1) & 1)) * INV_SQRT10;
}
__device__ __forceinline__ float pt_im(int p) {
    return (1.0f - 2.0f * (float)((p >> 2) & 1)) * (1.0f + 2.0f * (float)(p & 1)) * INV_SQRT10;
}

__global__ __launch_bounds__(256, 4)
void mmse_pic_kernel(const float* __restrict__ y_re, const float* __restrict__ y_im,
                     const float* __restrict__ h_re, const float* __restrict__ h_im,
                     const float* __restrict__ prior,
                     const float* __restrict__ s_re, const float* __restrict__ s_im,
                     float* __restrict__ out)
{
    const int lane = threadIdx.x & 63;
    const int w    = threadIdx.x >> 6;            // wave id in block (0-3)
    const int slA  = w << 1, slB = slA | 1;       // two batch slots per wave
    const size_t bsA = (size_t)(blockIdx.x * 8 + slA);
    const size_t bsB = bsA + 1;

    __shared__ float2 Sc[8][16][28];   // [S(0-15) | h(16-23) | y(24)] -> W after elim+scale
    __shared__ float2 xc_[8][8];
    __shared__ float2 ymc_[8][8];
    __shared__ float  vx_[8][8], ne_[8][8];
    __shared__ float  lsig[8][64];
    __shared__ float  logit_[8][8][20];
    __shared__ float  llrD_[8][8][4];

    // ---- load (vectorized, interleave re/im into float2), A then B ----
#define LOADPH(X) { \
        const float4* pr4 = (const float4*)(s_re + bs##X * 256); \
        const float4* pi4 = (const float4*)(s_im + bs##X * 256); \
        float4 vr = pr4[lane], vi = pi4[lane]; \
        int r = lane >> 2, c0 = (lane & 3) << 2; \
        Sc[sl##X][r][c0+0] = make_float2(vr.x, vi.x); \
        Sc[sl##X][r][c0+1] = make_float2(vr.y, vi.y); \
        Sc[sl##X][r][c0+2] = make_float2(vr.z, vi.z); \
        Sc[sl##X][r][c0+3] = make_float2(vr.w, vi.w); \
        if (lane < 32) { \
            const float4* hr4 = (const float4*)(h_re + bs##X * 128); \
            const float4* hi4 = (const float4*)(h_im + bs##X * 128); \
            float4 hr = hr4[lane], hi = hi4[lane]; \
            int row = lane >> 1, col = 16 + ((lane & 1) << 2); \
            Sc[sl##X][row][col+0] = make_float2(hr.x, hi.x); \
            Sc[sl##X][row][col+1] = make_float2(hr.y, hi.y); \
            Sc[sl##X][row][col+2] = make_float2(hr.z, hi.z); \
            Sc[sl##X][row][col+3] = make_float2(hr.w, hi.w); \
        } \
        if (lane < 16) Sc[sl##X][lane][24] = make_float2(y_re[bs##X*16+lane], y_im[bs##X*16+lane]); \
        if (lane < 32) ((float*)llrD_[sl##X])[lane] = prior[bs##X*32 + lane]; \
    }
    LOADPH(A) LOADPH(B)
#undef LOADPH
    WSYNC();

    // ---- forward-only unnormalized elimination on [S | h y], A/B interleaved ----
    {
        const int j0 = lane & 15;
        const int r4 = lane >> 4;
#define ELIMSTEP(X) { \
            float invd = rcpf(Sc[sl##X][k][k].x); \
            int j1 = k + 1 + j0, j2 = j1 + 16; \
            float2 rk0 = make_float2(0.f, 0.f), rk1 = make_float2(0.f, 0.f); \
            if (j1 < 25) rk0 = Sc[sl##X][k][j1]; \
            const bool blk2 = (k < 8); \
            if (blk2 && j2 < 25) rk1 = Sc[sl##X][k][j2]; \
            const int pmin = (k + 1) >> 2; \
            _Pragma("unroll") \
            for (int p = 0; p < 4; ++p) { \
                if (p < pmin) continue; \
                int i = (p << 2) + r4; \
                float2 aik = Sc[sl##X][i][k]; \
                float mr = aik.x * invd, mi = aik.y * invd; \
                if (i <= k) { mr = 0.f; mi = 0.f; } \
                if (j1 < 25) { \
                    float2 a = Sc[sl##X][i][j1]; \
                    a.x -= mr*rk0.x - mi*rk0.y; \
                    a.y -= mr*rk0.y + mi*rk0.x; \
                    Sc[sl##X][i][j1] = a; \
                } \
                if (blk2 && j2 < 25) { \
                    float2 a = Sc[sl##X][i][j2]; \
                    a.x -= mr*rk1.x - mi*rk1.y; \
                    a.y -= mr*rk1.y + mi*rk1.x; \
                    Sc[sl##X][i][j2] = a; \
                } \
            } }
        #pragma unroll
        for (int k = 0; k < 15; ++k) {
            ELIMSTEP(A)
            ELIMSTEP(B)
            WSYNC();
        }
#undef ELIMSTEP
    }
    // ---- scale RHS rows by rsqrt(d_m): W = D^-1/2 L^-1 [h|y] (= whitened) ----
    {
        int r2 = lane >> 2, c = lane & 3;
#define SCALEPH(X) { \
        float irs = rsqf(Sc[sl##X][r2][r2].x); \
        float2 v0 = Sc[sl##X][r2][16 + c]; \
        Sc[sl##X][r2][16 + c] = make_float2(v0.x*irs, v0.y*irs); \
        float2 v1 = Sc[sl##X][r2][20 + c]; \
        Sc[sl##X][r2][20 + c] = make_float2(v1.x*irs, v1.y*irs); \
        if (c == 0) { \
            float2 v2 = Sc[sl##X][r2][24]; \
            Sc[sl##X][r2][24] = make_float2(v2.x*irs, v2.y*irs); \
        } }
        SCALEPH(A) SCALEPH(B)
#undef SCALEPH
    }
    WSYNC();

    // ---- Gram g[i][j] (1 entry/lane), y_mf = Wh^H Wy, A/B interleaved ----
    const int s = lane >> 3, u = lane & 7;
    float g_reA = 0.f, g_imA = 0.f, ym_rA = 0.f, ym_iA = 0.f;
    float g_reB = 0.f, g_imB = 0.f, ym_rB = 0.f, ym_iB = 0.f;
#define GRAMPH(X) { \
    _Pragma("unroll") \
    for (int m = 0; m < 16; ++m) { \
        float2 a  = Sc[sl##X][m][16 + s]; \
        float2 x  = Sc[sl##X][m][16 + u]; \
        float2 xy = Sc[sl##X][m][24]; \
        g_re##X += a.x*x.x + a.y*x.y; \
        g_im##X += a.x*x.y - a.y*x.x; \
        ym_r##X += a.x*xy.x + a.y*xy.y; \
        ym_i##X += a.x*xy.y - a.y*xy.x; \
    } \
    if (u == 0) ymc_[sl##X][s] = make_float2(ym_r##X, ym_i##X); }
    GRAMPH(A) GRAMPH(B)
#undef GRAMPH
    WSYNC();

    const float pr = pt_re(u), pi2 = pt_im(u), pe = pr*pr + pi2*pi2;  // pt(u+8) = (-pr, pi2)
    float llr_a_regA = 0.f, llr_a_regB = 0.f;
    float l0A, l1A, l0B, l1B;

    for (int it = 0; it < 2; ++it) {
        // log-sigmoid table: one distinct value per lane
        {
            int ts = lane >> 3, tk = (lane >> 1) & 3, sg = lane & 1;
#define LSIGPH(X) { \
            float v = llrD_[sl##X][ts][tk]; \
            float x = sg ? v : -v; \
            lsig[sl##X][lane] = fminf(x, 0.f) - __logf(1.0f + __expf(-fabsf(x))); \
            if (lane < 32) llr_a_reg##X = ((float*)llrD_[sl##X])[lane]; }
            LSIGPH(A) LSIGPH(B)
#undef LSIGPH
        }
        WSYNC();
        // symbol logits + moments (butterfly over 8 lanes of stream s)
        {
            int base = s << 3;
#define MOMPH(X) { \
            float lc = lsig[sl##X][base | 2 | ((u >> 2) & 1)] \
                     + lsig[sl##X][base | 4 | ((u >> 1) & 1)] \
                     + lsig[sl##X][base | 6 | (u & 1)]; \
            l0##X = lc + lsig[sl##X][base]; \
            l1##X = lc + lsig[sl##X][base | 1]; \
            float mx = fmaxf(l0##X, l1##X); \
            mx = fmaxf(mx, swzf<SWX1>(mx)); \
            mx = fmaxf(mx, swzf<SWX2>(mx)); \
            mx = fmaxf(mx, swzf<SWX4>(mx)); \
            float w0 = __expf(l0##X - mx), w1 = __expf(l1##X - mx); \
            float a = w0 + w1, dw = w0 - w1; \
            float se = a, mr = dw * pr, mi = a * pi2, e2 = a * pe; \
            se += swzf<SWX1>(se); mr += swzf<SWX1>(mr); mi += swzf<SWX1>(mi); e2 += swzf<SWX1>(e2); \
            se += swzf<SWX2>(se); mr += swzf<SWX2>(mr); mi += swzf<SWX2>(mi); e2 += swzf<SWX2>(e2); \
            se += swzf<SWX4>(se); mr += swzf<SWX4>(mr); mi += swzf<SWX4>(mi); e2 += swzf<SWX4>(e2); \
            if (u == 0) { \
                float inv = rcpf(se); \
                float mxr = mr*inv, mxi = mi*inv; \
                xc_[sl##X][s] = make_float2(mxr, mxi); \
                vx_[sl##X][s] = e2*inv - (mxr*mxr + mxi*mxi); \
            } }
            MOMPH(A) MOMPH(B)
#undef MOMPH
        }
        WSYNC();
        // setup + inner GJ + extraction, A then B (independent chains)
#define GJ_STEP(X, K) { \
            float pvr = rdlane(Ar##X, (K)*9), pvi = rdlane(Ai##X, (K)*9); \
            int rowsrc = ((K)<<3)|u; \
            float rAr = __shfl(Ar##X, rowsrc), rAi = __shfl(Ai##X, rowsrc); \
            float rCr = __shfl(Cr##X, rowsrc), rCi = __shfl(Ci##X, rowsrc); \
            float rbr = __shfl(br##X, rowsrc), rbi = __shfl(bi##X, rowsrc); \
            float cAr = swzf<(((K)<<5)|0x18)>(Ar##X), cAi = swzf<(((K)<<5)|0x18)>(Ai##X); \
            float id2 = rcpf(pvr*pvr + pvi*pvi); \
            float ipr2 = pvr*id2, ipi2 = -pvi*id2; \
            float mr2 = cAr*ipr2 - cAi*ipi2; \
            float mi2 = cAr*ipi2 + cAi*ipr2; \
            if (s == (K)) { mr2 = 0.f; mi2 = 0.f; } \
            Ar##X -= mr2*rAr - mi2*rAi;  Ai##X -= mr2*rAi + mi2*rAr; \
            Cr##X -= mr2*rCr - mi2*rCi;  Ci##X -= mr2*rCi + mi2*rCr; \
            br##X -= mr2*rbr - mi2*rbi;  bi##X -= mr2*rbi + mi2*rbr; }
#define SOLVEPH(X) \
        float2 xj##X = xc_[sl##X][u]; \
        { \
            float vj = vx_[sl##X][u]; \
            float tr = g_re##X*xj##X.x - g_im##X*xj##X.y; \
            float ti = g_re##X*xj##X.y + g_im##X*xj##X.x; \
            tr += swzf<SWX1>(tr); ti += swzf<SWX1>(ti); \
            tr += swzf<SWX2>(tr); ti += swzf<SWX2>(ti); \
            tr += swzf<SWX4>(tr); ti += swzf<SWX4>(ti); \
            float2 ym = ymc_[sl##X][s]; \
            float br##X = ym.x - tr, bi##X = ym.y - ti; \
            float Ar##X = g_re##X*vj + ((s == u) ? 1.f : 0.f); \
            float Ai##X = g_im##X*vj; \
            float Cr##X = g_re##X, Ci##X = g_im##X; \
            GJ_STEP(X,0) GJ_STEP(X,1) GJ_STEP(X,2) GJ_STEP(X,3) \
            GJ_STEP(X,4) GJ_STEP(X,5) GJ_STEP(X,6) GJ_STEP(X,7) \
            if (s == u) { \
                float id3 = rcpf(Ar##X*Ar##X + Ai##X*Ai##X); \
                float ipr3 = Ar##X*id3, ipi3 = -Ai##X*id3; \
                float wr = br##X*ipr3 - bi##X*ipi3; \
                float wi = br##X*ipi3 + bi##X*ipr3; \
                float ccr = Cr##X*ipr3 - Ci##X*ipi3; \
                float cci = Cr##X*ipi3 + Ci##X*ipr3; \
                float mu = ccr; \
                float im = rcpf(mu); \
                float zr = (wr + ccr*xj##X.x - cci*xj##X.y) * im; \
                float zi = (wi + ccr*xj##X.y + cci*xj##X.x) * im; \
                xc_[sl##X][s] = make_float2(zr, zi); \
                ne_[sl##X][s] = fmaxf(1.f - vx_[sl##X][s]*mu, EPS_F) * im; \
            } \
        }
        SOLVEPH(A)
        SOLVEPH(B)
#undef SOLVEPH
#undef GJ_STEP
        WSYNC();
        // demap: 2 points per lane
#define DEMAPPH(X) { \
            float2 xh = xc_[sl##X][s]; \
            float idn = rcpf(ne_[sl##X][s]); \
            float dr0 = xh.x - pr, dr1 = xh.x + pr, di = xh.y - pi2; \
            logit_[sl##X][s][u]     = l0##X - (dr0*dr0 + di*di) * idn; \
            logit_[sl##X][s][u + 8] = l1##X - (dr1*dr1 + di*di) * idn; }
        DEMAPPH(A) DEMAPPH(B)
#undef DEMAPPH
        WSYNC();
        // max-log LLR: lane = (s2, bit kb, half); max over 8 matching points
        {
            int s2 = lane >> 3, kb = (lane >> 1) & 3, half = lane & 1;
            int bitpos = 3 - kb;
#define LLRPH(X) { \
            float m = -1e30f; \
            _Pragma("unroll") \
            for (int q = 0; q < 8; ++q) { \
                int low  = q & ((1 << bitpos) - 1); \
                int high = (q >> bitpos) << (bitpos + 1); \
                int p = high | (half << bitpos) | low; \
                m = fmaxf(m, logit_[sl##X][s2][p]); \
            } \
            float other = swzf<SWX1>(m); \
            if (half == 1) llrD_[sl##X][s2][kb] = m - other; }
            LLRPH(A) LLRPH(B)
#undef LLRPH
        }
        WSYNC();
    }

    if (lane < 32) {
        out[bsA*32 + lane] = ((float*)llrD_[slA])[lane] - llr_a_regA;
        out[bsB*32 + lane] = ((float*)llrD_[slB])[lane] - llr_a_regB;
    }
}

extern "C" void kernel_launch(void* const* d_in, const int* in_sizes, int n_in,
                              void* d_out, int out_size, void* d_ws, size_t ws_size,
                              hipStream_t stream) {
    const float* y_re  = (const float*)d_in[0];
    const float* y_im  = (const float*)d_in[1];
    const float* h_re  = (const float*)d_in[2];
    const float* h_im  = (const float*)d_in[3];
    const float* prior = (const float*)d_in[4];
    const float* s_re  = (const float*)d_in[5];
    const float* s_im  = (const float*)d_in[6];
    float* out = (float*)d_out;

    const int B = in_sizes[0] / 16;
    // 4096 blocks x 4 waves x 2 batches/wave = 32768 batches, straight-line.
    // LDS 38.4KB/block -> 4 blocks/CU = 32 batch-contexts/CU.
    mmse_pic_kernel<<<dim3(B / 8), dim3(256), 0, stream>>>(
        y_re, y_im, h_re, h_im, prior, s_re, s_im, out);
}